// Round 4
// baseline (938.903 us; speedup 1.0000x reference)
//
#include <hip/hip_runtime.h>
#include <hip/hip_fp16.h>

#define DB    768
#define SEQ   2048
#define BATCH 8
#define NTOK  (BATCH*SEQ)      // 16384
#define NFUSE (3*DB)           // 2304 fused QKV output columns
#define NORM_F 0.036084391824351613f

typedef __attribute__((ext_vector_type(8))) short  short8;
typedef __attribute__((ext_vector_type(4))) short  short4v;
typedef __attribute__((ext_vector_type(4))) float  f32x4;
typedef __attribute__((ext_vector_type(4))) float  float4v;

__device__ __forceinline__ unsigned short f2bf(float f) {
  unsigned int u = __float_as_uint(f);
  u += 0x7fffu + ((u >> 16) & 1u);
  return (unsigned short)(u >> 16);
}
__device__ __forceinline__ float bf2f(unsigned short h) {
  return __uint_as_float(((unsigned int)h) << 16);
}
__device__ __forceinline__ float h2f_bits(unsigned short h) {
  __half v; __builtin_memcpy(&v, &h, 2); return __half2float(v);
}
__device__ __forceinline__ unsigned short f2h_bits(float f) {
  __half v = __float2half(f); unsigned short u; __builtin_memcpy(&u, &v, 2); return u;
}

// =============================================================================
// wsplit: W[d][n] (3 weights) -> fused WT[nf][d] bf16 hi/lo, via LDS transpose.
// =============================================================================
__global__ __launch_bounds__(256) void wsplit_kernel(
    const float* __restrict__ Wq, const float* __restrict__ Wk,
    const float* __restrict__ Wv,
    unsigned short* __restrict__ WTh, unsigned short* __restrict__ WTl) {
  __shared__ float T[64][68];
  int bx = blockIdx.x;
  int w = bx / 144, rem = bx % 144;
  int d0 = (rem / 12) * 64, n0 = (rem % 12) * 64;
  const float* W = (w == 0) ? Wq : ((w == 1) ? Wk : Wv);
  int t = threadIdx.x;
  int dl = t >> 4, n4 = (t & 15) * 4;
#pragma unroll
  for (int j = 0; j < 4; j++) {
    float4v v = *(const float4v*)(W + (size_t)(d0 + dl + j * 16) * DB + n0 + n4);
    *(float4v*)&T[dl + j * 16][n4] = v;
  }
  __syncthreads();
  int nl = t >> 2, dc = (t & 3) * 16;
  short8 hb[2], lb[2];
#pragma unroll
  for (int e = 0; e < 16; e++) {
    float v = T[dc + e][nl];
    unsigned short h = f2bf(v);
    hb[e >> 3][e & 7] = (short)h;
    lb[e >> 3][e & 7] = (short)f2bf(v - bf2f(h));
  }
  size_t o = ((size_t)w * DB + n0 + nl) * DB + d0 + dc;
  *(short8*)(WTh + o) = hb[0]; *(short8*)(WTh + o + 8) = hb[1];
  *(short8*)(WTl + o) = lb[0]; *(short8*)(WTl + o + 8) = lb[1];
}

// =============================================================================
// xsplit: X fp32 -> Xh/Xl bf16, once.
// =============================================================================
__global__ __launch_bounds__(256) void xsplit_kernel(
    const float* __restrict__ X,
    unsigned short* __restrict__ Xh, unsigned short* __restrict__ Xl) {
  size_t i4 = ((size_t)blockIdx.x * 256 + threadIdx.x) * 4;
  float4v v = *(const float4v*)(X + i4);
  short4v h, l;
#pragma unroll
  for (int j = 0; j < 4; j++) {
    unsigned short hh = f2bf(v[j]);
    h[j] = (short)hh;
    l[j] = (short)f2bf(v[j] - bf2f(hh));
  }
  *(short4v*)(Xh + i4) = h;
  *(short4v*)(Xl + i4) = l;
}

// =============================================================================
// compact: per batch, list of unmasked q indices (ascending) + count.
// =============================================================================
__global__ __launch_bounds__(256) void compact_kernel(
    const int* __restrict__ mask, int* __restrict__ idx, int* __restrict__ cnt) {
  int b = blockIdx.x, t = threadIdx.x;
  const int* m = mask + b * SEQ;
  __shared__ int pref[256];
  int mv[8], c = 0, base = t * 8;
#pragma unroll
  for (int j = 0; j < 8; j++) { mv[j] = (m[base + j] != 0); c += mv[j]; }
  pref[t] = c;
  __syncthreads();
  for (int off = 1; off < 256; off <<= 1) {
    int add = (t >= off) ? pref[t - off] : 0;
    __syncthreads();
    pref[t] += add;
    __syncthreads();
  }
  int o = pref[t] - c;
  int* ib = idx + b * SEQ;
#pragma unroll
  for (int j = 0; j < 8; j++) if (mv[j]) ib[o++] = base + j;
  if (t == 255) cnt[b] = pref[255];
}

// =============================================================================
// proj: fused QKV GEMM, NO LDS: MFMA fragments loaded straight from global
// (row-major layout matches A/B frag pattern: 16B/lane, 16 rows x 64B/wave).
// Ping-pong register prefetch; no barriers in the K-loop.
// =============================================================================
__global__ __launch_bounds__(256, 2) void proj_kernel(
    const unsigned short* __restrict__ Xh, const unsigned short* __restrict__ Xl,
    const unsigned short* __restrict__ WTh, const unsigned short* __restrict__ WTl,
    const float* __restrict__ bq, const float* __restrict__ bk,
    const float* __restrict__ bv,
    unsigned short* __restrict__ Qh, unsigned short* __restrict__ Ql,
    unsigned short* __restrict__ Kh, unsigned short* __restrict__ Kl,
    unsigned short* __restrict__ VT) {
  int n0 = blockIdx.x << 7;
  int m0 = blockIdx.y << 7;
  int tid = threadIdx.x;
  int wave = tid >> 6, lane = tid & 63;
  int wm = wave & 1, wn = wave >> 1;
  int quad = lane >> 4, l16 = lane & 15;

  int aoff[4], boff[4];
#pragma unroll
  for (int mi = 0; mi < 4; mi++)
    aoff[mi] = (m0 + wm * 64 + mi * 16 + l16) * DB + quad * 8;
#pragma unroll
  for (int ni = 0; ni < 4; ni++)
    boff[ni] = (n0 + wn * 64 + ni * 16 + l16) * DB + quad * 8;

  f32x4 acc[4][4];
#pragma unroll
  for (int mi = 0; mi < 4; mi++)
#pragma unroll
    for (int ni = 0; ni < 4; ni++) acc[mi][ni] = (f32x4){0.f, 0.f, 0.f, 0.f};

  short8 ah[2][4], al[2][4], bh[2][4], bl[2][4];
  auto lda = [&](int s, int kt) {
#pragma unroll
    for (int mi = 0; mi < 4; mi++) {
      ah[s][mi] = *(const short8*)(Xh + aoff[mi] + kt);
      al[s][mi] = *(const short8*)(Xl + aoff[mi] + kt);
    }
#pragma unroll
    for (int ni = 0; ni < 4; ni++) {
      bh[s][ni] = *(const short8*)(WTh + boff[ni] + kt);
      bl[s][ni] = *(const short8*)(WTl + boff[ni] + kt);
    }
  };
  auto cmp = [&](int s) {
#pragma unroll
    for (int mi = 0; mi < 4; mi++)
#pragma unroll
      for (int ni = 0; ni < 4; ni++) {
        acc[mi][ni] = __builtin_amdgcn_mfma_f32_16x16x32_bf16(ah[s][mi], bh[s][ni], acc[mi][ni], 0, 0, 0);
        acc[mi][ni] = __builtin_amdgcn_mfma_f32_16x16x32_bf16(ah[s][mi], bl[s][ni], acc[mi][ni], 0, 0, 0);
        acc[mi][ni] = __builtin_amdgcn_mfma_f32_16x16x32_bf16(al[s][mi], bh[s][ni], acc[mi][ni], 0, 0, 0);
      }
  };

  lda(0, 0);
#pragma unroll 1
  for (int kt = 0; kt < DB - 64; kt += 64) {   // pairs; prefetch next while computing
    lda(1, kt + 32);  cmp(0);
    lda(0, kt + 64);  cmp(1);
  }
  lda(1, DB - 32);  cmp(0);  cmp(1);

  int z = n0 / DB;
  int nl0 = n0 - z * DB;
  const float* bias = (z == 0) ? bq : ((z == 1) ? bk : bv);
#pragma unroll
  for (int mi = 0; mi < 4; mi++)
#pragma unroll
    for (int ni = 0; ni < 4; ni++)
#pragma unroll
      for (int r = 0; r < 4; r++) {
        int gm = m0 + wm * 64 + mi * 16 + quad * 4 + r;
        int ln = nl0 + wn * 64 + ni * 16 + l16;
        float val = acc[mi][ni][r] + bias[ln];
        unsigned short h = f2bf(val);
        if (z == 0) {
          Qh[(size_t)gm * DB + ln] = h;
          Ql[(size_t)gm * DB + ln] = f2bf(val - bf2f(h));
        } else if (z == 1) {
          Kh[(size_t)gm * DB + ln] = h;
          Kl[(size_t)gm * DB + ln] = f2bf(val - bf2f(h));
        } else {
          int bb = gm >> 11, s = gm & 2047;
          VT[((size_t)bb * DB + ln) * SEQ + s] = h;
        }
      }
}

// =============================================================================
// vmean: Vmean[b][n] = mean_s VT[b][n][s].
// =============================================================================
__global__ __launch_bounds__(256) void vmean_kernel(
    const unsigned short* __restrict__ VT, float* __restrict__ Vmean) {
  int bn = blockIdx.x;
  const unsigned short* p = VT + (size_t)bn * SEQ;
  int t = threadIdx.x, wave = t >> 6, lane = t & 63;
  short8 hv = *(const short8*)(p + t * 8);
  float s = 0.f;
#pragma unroll
  for (int j = 0; j < 8; j++) s += bf2f((unsigned short)hv[j]);
#pragma unroll
  for (int off = 32; off >= 1; off >>= 1) s += __shfl_down(s, off);
  __shared__ float red[4];
  if (lane == 0) red[wave] = s;
  __syncthreads();
  if (t == 0) Vmean[bn] = (red[0] + red[1] + red[2] + red[3]) * (1.0f / SEQ);
}

// =============================================================================
// scores (compacted q): SC[b][qc][t] = Q[idx[qc]] . K[t], fp16.  No LDS.
// =============================================================================
__global__ __launch_bounds__(256, 2) void scores_kernel(
    const unsigned short* __restrict__ Qh, const unsigned short* __restrict__ Ql,
    const unsigned short* __restrict__ Kh, const unsigned short* __restrict__ Kl,
    const int* __restrict__ idx, const int* __restrict__ cnt,
    unsigned short* __restrict__ SC) {
  int b = blockIdx.z;
  int cb = cnt[b];
  int q0 = blockIdx.y << 7;
  if (q0 >= cb) return;
  int t0 = blockIdx.x << 7;
  int tid = threadIdx.x;
  int wave = tid >> 6, lane = tid & 63;
  int wm = wave & 1, wn = wave >> 1;
  int quad = lane >> 4, l16 = lane & 15;

  int aoff[4], boff[4];
#pragma unroll
  for (int mi = 0; mi < 4; mi++) {
    int qr = q0 + wm * 64 + mi * 16 + l16;
    if (qr >= cb) qr = cb - 1;                 // clamp tail (writes guarded)
    int gq = idx[b * SEQ + qr];
    aoff[mi] = (b * SEQ + gq) * DB + quad * 8;
  }
#pragma unroll
  for (int ni = 0; ni < 4; ni++)
    boff[ni] = (b * SEQ + t0 + wn * 64 + ni * 16 + l16) * DB + quad * 8;

  f32x4 acc[4][4];
#pragma unroll
  for (int mi = 0; mi < 4; mi++)
#pragma unroll
    for (int ni = 0; ni < 4; ni++) acc[mi][ni] = (f32x4){0.f, 0.f, 0.f, 0.f};

  short8 ah[2][4], al[2][4], bh[2][4], bl[2][4];
  auto lda = [&](int s, int kt) {
#pragma unroll
    for (int mi = 0; mi < 4; mi++) {
      ah[s][mi] = *(const short8*)(Qh + aoff[mi] + kt);
      al[s][mi] = *(const short8*)(Ql + aoff[mi] + kt);
    }
#pragma unroll
    for (int ni = 0; ni < 4; ni++) {
      bh[s][ni] = *(const short8*)(Kh + boff[ni] + kt);
      bl[s][ni] = *(const short8*)(Kl + boff[ni] + kt);
    }
  };
  auto cmp = [&](int s) {
#pragma unroll
    for (int mi = 0; mi < 4; mi++)
#pragma unroll
      for (int ni = 0; ni < 4; ni++) {
        acc[mi][ni] = __builtin_amdgcn_mfma_f32_16x16x32_bf16(ah[s][mi], bh[s][ni], acc[mi][ni], 0, 0, 0);
        acc[mi][ni] = __builtin_amdgcn_mfma_f32_16x16x32_bf16(ah[s][mi], bl[s][ni], acc[mi][ni], 0, 0, 0);
        acc[mi][ni] = __builtin_amdgcn_mfma_f32_16x16x32_bf16(al[s][mi], bh[s][ni], acc[mi][ni], 0, 0, 0);
      }
  };

  lda(0, 0);
#pragma unroll 1
  for (int kt = 0; kt < DB - 64; kt += 64) {
    lda(1, kt + 32);  cmp(0);
    lda(0, kt + 64);  cmp(1);
  }
  lda(1, DB - 32);  cmp(0);  cmp(1);

#pragma unroll
  for (int mi = 0; mi < 4; mi++)
#pragma unroll
    for (int r = 0; r < 4; r++) {
      int qc = q0 + wm * 64 + mi * 16 + quad * 4 + r;
      if (qc < cb) {
#pragma unroll
        for (int ni = 0; ni < 4; ni++) {
          int gt = t0 + wn * 64 + ni * 16 + l16;
          SC[((size_t)b * SEQ + qc) * SEQ + gt] = f2h_bits(acc[mi][ni][r]);
        }
      }
    }
}

// =============================================================================
// softmax on compacted rows, fp16 -> bf16 * NORM in place.
// =============================================================================
__global__ __launch_bounds__(256) void softmax_kernel(
    unsigned short* __restrict__ SC, const int* __restrict__ cnt) {
  int b = blockIdx.x >> 11, qc = blockIdx.x & 2047;
  if (qc >= cnt[b]) return;
  unsigned short* p = SC + ((size_t)b * SEQ + qc) * SEQ;
  int tid = threadIdx.x;

  short8 hv = *(const short8*)(p + (tid << 3));
  float v[8];
#pragma unroll
  for (int j = 0; j < 8; j++) v[j] = h2f_bits((unsigned short)hv[j]);

  float m = v[0];
#pragma unroll
  for (int j = 1; j < 8; j++) m = fmaxf(m, v[j]);
#pragma unroll
  for (int off = 32; off >= 1; off >>= 1) m = fmaxf(m, __shfl_down(m, off));

  __shared__ float red[8];
  int w = tid >> 6;
  if ((tid & 63) == 0) red[w] = m;
  __syncthreads();
  m = fmaxf(fmaxf(red[0], red[1]), fmaxf(red[2], red[3]));

  float e[8], s = 0.f;
#pragma unroll
  for (int j = 0; j < 8; j++) { e[j] = __expf(v[j] - m); s += e[j]; }
#pragma unroll
  for (int off = 32; off >= 1; off >>= 1) s += __shfl_down(s, off);
  if ((tid & 63) == 0) red[4 + w] = s;
  __syncthreads();
  float L = red[4] + red[5] + red[6] + red[7];

  float scale = NORM_F / L;
  short8 ov;
#pragma unroll
  for (int j = 0; j < 8; j++) ov[j] = (short)f2bf(e[j] * scale);
  *(short8*)(p + (tid << 3)) = ov;
}

// =============================================================================
// fill: masked rows get NORM * mean(V).
// =============================================================================
__global__ __launch_bounds__(256) void fill_kernel(
    const int* __restrict__ mask, const float* __restrict__ Vmean,
    float* __restrict__ out) {
  int row = blockIdx.x;
  if (mask[row] != 0) return;
  const float* vm = Vmean + (row >> 11) * DB;
  float* o = out + (size_t)row * DB;
  for (int n = threadIdx.x; n < DB; n += 256) o[n] = vm[n] * NORM_F;
}

// =============================================================================
// pv (compacted): out[idx[qc]][v] = sum_t attn[qc][t] * V[t][v].  No LDS.
// A rows >= cb contain stale garbage; MFMA rows are independent, writes guarded.
// =============================================================================
__global__ __launch_bounds__(256, 2) void pv_kernel(
    const unsigned short* __restrict__ SC, const unsigned short* __restrict__ VT,
    const int* __restrict__ idx, const int* __restrict__ cnt,
    float* __restrict__ out) {
  int b = blockIdx.z;
  int cb = cnt[b];
  int q0 = blockIdx.y << 7;
  if (q0 >= cb) return;
  int v0 = blockIdx.x << 7;
  int tid = threadIdx.x;
  int wave = tid >> 6, lane = tid & 63;
  int wm = wave & 1, wn = wave >> 1;
  int quad = lane >> 4, l16 = lane & 15;

  int aoff[4], boff[4];
#pragma unroll
  for (int mi = 0; mi < 4; mi++)
    aoff[mi] = (b * SEQ + q0 + wm * 64 + mi * 16 + l16) * SEQ + quad * 8;
#pragma unroll
  for (int ni = 0; ni < 4; ni++)
    boff[ni] = (b * DB + v0 + wn * 64 + ni * 16 + l16) * SEQ + quad * 8;

  f32x4 acc[4][4];
#pragma unroll
  for (int mi = 0; mi < 4; mi++)
#pragma unroll
    for (int ni = 0; ni < 4; ni++) acc[mi][ni] = (f32x4){0.f, 0.f, 0.f, 0.f};

  short8 af[2][4], bf[2][4];
  auto lda = [&](int s, int kt) {
#pragma unroll
    for (int mi = 0; mi < 4; mi++) af[s][mi] = *(const short8*)(SC + (size_t)aoff[mi] + kt);
#pragma unroll
    for (int ni = 0; ni < 4; ni++) bf[s][ni] = *(const short8*)(VT + (size_t)boff[ni] + kt);
  };
  auto cmp = [&](int s) {
#pragma unroll
    for (int mi = 0; mi < 4; mi++)
#pragma unroll
      for (int ni = 0; ni < 4; ni++)
        acc[mi][ni] = __builtin_amdgcn_mfma_f32_16x16x32_bf16(af[s][mi], bf[s][ni], acc[mi][ni], 0, 0, 0);
  };

  lda(0, 0);
#pragma unroll 1
  for (int kt = 0; kt < SEQ - 64; kt += 64) {
    lda(1, kt + 32);  cmp(0);
    lda(0, kt + 64);  cmp(1);
  }
  lda(1, SEQ - 32);  cmp(0);  cmp(1);

#pragma unroll
  for (int mi = 0; mi < 4; mi++)
#pragma unroll
    for (int r = 0; r < 4; r++) {
      int qc = q0 + wm * 64 + mi * 16 + quad * 4 + r;
      if (qc < cb) {
        int q = idx[b * SEQ + qc];
#pragma unroll
        for (int ni = 0; ni < 4; ni++) {
          int gv = v0 + wn * 64 + ni * 16 + l16;
          out[((size_t)b * SEQ + q) * DB + gv] = acc[mi][ni][r];
        }
      }
    }
}

// =============================================================================
extern "C" void kernel_launch(void* const* d_in, const int* in_sizes, int n_in,
                              void* d_out, int out_size, void* d_ws, size_t ws_size,
                              hipStream_t stream) {
  const float* x    = (const float*)d_in[0];
  const int*   mask = (const int*)d_in[1];
  const float* Wq   = (const float*)d_in[2];
  const float* bq   = (const float*)d_in[3];
  const float* Wk   = (const float*)d_in[4];
  const float* bk   = (const float*)d_in[5];
  const float* Wv   = (const float*)d_in[6];
  const float* bv   = (const float*)d_in[7];
  float* out = (float*)d_out;
  char* ws = (char*)d_ws;

  // Workspace (~184 MB). SC region [0, 67.1MB) is reused: Xh/Xl/WTh/WTl live
  // there only until proj completes; scores then overwrites it with SC.
  const size_t TOK2 = (size_t)NTOK * DB * 2;                 // 25,165,824 B
  unsigned short* SC  = (unsigned short*)ws;
  unsigned short* Xh  = (unsigned short*)ws;
  unsigned short* Xl  = (unsigned short*)(ws + TOK2);
  unsigned short* WTh = (unsigned short*)(ws + 2 * TOK2);
  unsigned short* WTl = (unsigned short*)(ws + 2 * TOK2 + (size_t)NFUSE * DB * 2);
  const size_t SCSZ = (size_t)BATCH * SEQ * SEQ * 2;         // 67,108,864 B
  unsigned short* Qh = (unsigned short*)(ws + SCSZ);
  unsigned short* Ql = Qh + (size_t)NTOK * DB;
  unsigned short* Kh = Ql + (size_t)NTOK * DB;
  unsigned short* Kl = Kh + (size_t)NTOK * DB;
  unsigned short* VT = Kl + (size_t)NTOK * DB;
  int*   idx   = (int*)(ws + SCSZ + 5 * TOK2);
  int*   cnt   = idx + NTOK;
  float* Vmean = (float*)(cnt + 16);

  wsplit_kernel<<<432, 256, 0, stream>>>(Wq, Wk, Wv, WTh, WTl);
  xsplit_kernel<<<NTOK * DB / 1024, 256, 0, stream>>>(x, Xh, Xl);
  compact_kernel<<<BATCH, 256, 0, stream>>>(mask, idx, cnt);
  proj_kernel<<<dim3(NFUSE / 128, NTOK / 128), 256, 0, stream>>>(
      Xh, Xl, WTh, WTl, bq, bk, bv, Qh, Ql, Kh, Kl, VT);
  vmean_kernel<<<BATCH * DB, 256, 0, stream>>>(VT, Vmean);
  scores_kernel<<<dim3(SEQ / 128, SEQ / 128, BATCH), 256, 0, stream>>>(
      Qh, Ql, Kh, Kl, idx, cnt, SC);
  softmax_kernel<<<NTOK, 256, 0, stream>>>(SC, cnt);
  fill_kernel<<<NTOK, 256, 0, stream>>>(mask, Vmean, out);
  pv_kernel<<<dim3(DB / 128, SEQ / 128, BATCH), 256, 0, stream>>>(
      SC, VT, idx, cnt, out);
}

// Round 5
// 487.502 us; speedup vs baseline: 1.9259x; 1.9259x over previous
//
#include <hip/hip_runtime.h>
#include <hip/hip_fp16.h>

#define DB    768
#define SEQ   2048
#define BATCH 8
#define NTOK  (BATCH*SEQ)      // 16384
#define NFUSE (3*DB)           // 2304 fused QKV output columns
#define NORM_F 0.036084391824351613f
#define ASCALE 512.0f          // attn stored *512 in fp16 to dodge denorm flush
#define INV_ASCALE (1.0f/512.0f)

typedef __attribute__((ext_vector_type(8))) short    short8;
typedef __attribute__((ext_vector_type(4))) short    short4v;
typedef __attribute__((ext_vector_type(8))) _Float16 half8;
typedef __attribute__((ext_vector_type(4))) float    f32x4;
typedef __attribute__((ext_vector_type(4))) float    float4v;

__device__ __forceinline__ unsigned short f2bf(float f) {
  unsigned int u = __float_as_uint(f);
  u += 0x7fffu + ((u >> 16) & 1u);
  return (unsigned short)(u >> 16);
}
__device__ __forceinline__ float bf2f(unsigned short h) {
  return __uint_as_float(((unsigned int)h) << 16);
}
__device__ __forceinline__ float h2f_bits(unsigned short h) {
  __half v; __builtin_memcpy(&v, &h, 2); return __half2float(v);
}
__device__ __forceinline__ unsigned short f2h_bits(float f) {
  __half v = __float2half(f); unsigned short u; __builtin_memcpy(&u, &v, 2); return u;
}

// =============================================================================
// wsplit: W[d][n] (3 weights) -> fused WT[nf][d] bf16 hi/lo, via LDS transpose.
// =============================================================================
__global__ __launch_bounds__(256) void wsplit_kernel(
    const float* __restrict__ Wq, const float* __restrict__ Wk,
    const float* __restrict__ Wv,
    unsigned short* __restrict__ WTh, unsigned short* __restrict__ WTl) {
  __shared__ float T[64][68];
  int bx = blockIdx.x;
  int w = bx / 144, rem = bx % 144;
  int d0 = (rem / 12) * 64, n0 = (rem % 12) * 64;
  const float* W = (w == 0) ? Wq : ((w == 1) ? Wk : Wv);
  int t = threadIdx.x;
  int dl = t >> 4, n4 = (t & 15) * 4;
#pragma unroll
  for (int j = 0; j < 4; j++) {
    float4v v = *(const float4v*)(W + (size_t)(d0 + dl + j * 16) * DB + n0 + n4);
    *(float4v*)&T[dl + j * 16][n4] = v;
  }
  __syncthreads();
  int nl = t >> 2, dc = (t & 3) * 16;
  short8 hb[2], lb[2];
#pragma unroll
  for (int e = 0; e < 16; e++) {
    float v = T[dc + e][nl];
    unsigned short h = f2bf(v);
    hb[e >> 3][e & 7] = (short)h;
    lb[e >> 3][e & 7] = (short)f2bf(v - bf2f(h));
  }
  size_t o = ((size_t)w * DB + n0 + nl) * DB + d0 + dc;
  *(short8*)(WTh + o) = hb[0]; *(short8*)(WTh + o + 8) = hb[1];
  *(short8*)(WTl + o) = lb[0]; *(short8*)(WTl + o + 8) = lb[1];
}

// =============================================================================
// xsplit: X fp32 -> Xh/Xl bf16, once.
// =============================================================================
__global__ __launch_bounds__(256) void xsplit_kernel(
    const float* __restrict__ X,
    unsigned short* __restrict__ Xh, unsigned short* __restrict__ Xl) {
  size_t i4 = ((size_t)blockIdx.x * 256 + threadIdx.x) * 4;
  float4v v = *(const float4v*)(X + i4);
  short4v h, l;
#pragma unroll
  for (int j = 0; j < 4; j++) {
    unsigned short hh = f2bf(v[j]);
    h[j] = (short)hh;
    l[j] = (short)f2bf(v[j] - bf2f(hh));
  }
  *(short4v*)(Xh + i4) = h;
  *(short4v*)(Xl + i4) = l;
}

// =============================================================================
// compact: per batch, list of unmasked q indices (ascending) + count.
// =============================================================================
__global__ __launch_bounds__(256) void compact_kernel(
    const int* __restrict__ mask, int* __restrict__ idx, int* __restrict__ cnt) {
  int b = blockIdx.x, t = threadIdx.x;
  const int* m = mask + b * SEQ;
  __shared__ int pref[256];
  int mv[8], c = 0, base = t * 8;
#pragma unroll
  for (int j = 0; j < 8; j++) { mv[j] = (m[base + j] != 0); c += mv[j]; }
  pref[t] = c;
  __syncthreads();
  for (int off = 1; off < 256; off <<= 1) {
    int add = (t >= off) ? pref[t - off] : 0;
    __syncthreads();
    pref[t] += add;
    __syncthreads();
  }
  int o = pref[t] - c;
  int* ib = idx + b * SEQ;
#pragma unroll
  for (int j = 0; j < 8; j++) if (mv[j]) ib[o++] = base + j;
  if (t == 255) cnt[b] = pref[255];
}

// =============================================================================
// proj: fused QKV GEMM.  Split-bf16 3-MFMA (fp32-grade accuracy), outputs
// single fp16 Qf/Kf + fp16 VT.  R1-style classic LDS staging (fastest measured)
// + VGPR prefetch of next K-tile overlapping the MFMA block.
// =============================================================================
__global__ __launch_bounds__(256) void proj_kernel(
    const unsigned short* __restrict__ Xh, const unsigned short* __restrict__ Xl,
    const unsigned short* __restrict__ WTh, const unsigned short* __restrict__ WTl,
    const float* __restrict__ bq, const float* __restrict__ bk,
    const float* __restrict__ bv,
    unsigned short* __restrict__ Qf, unsigned short* __restrict__ Kf,
    unsigned short* __restrict__ VT) {
  __shared__ unsigned short Ah[128 * 40], Al[128 * 40];   // pad 32->40 (2-way ok)
  __shared__ unsigned short Bh[128 * 40], Bl[128 * 40];   // 40 KB total
  int n0 = blockIdx.x << 7;
  int m0 = blockIdx.y << 7;
  int tid = threadIdx.x;
  int wave = tid >> 6, lane = tid & 63;
  int wm = wave & 1, wn = wave >> 1;
  int quad = lane >> 4, l16 = lane & 15;

  size_t ga[2], gb[2]; int lofs[2];
#pragma unroll
  for (int r = 0; r < 2; r++) {
    int ix = (r << 11) + (tid << 3);
    int row = ix >> 5, col = ix & 31;
    ga[r] = (size_t)(m0 + row) * DB + col;
    gb[r] = (size_t)(n0 + row) * DB + col;
    lofs[r] = row * 40 + col;
  }

  f32x4 acc[4][4];
#pragma unroll
  for (int mi = 0; mi < 4; mi++)
#pragma unroll
    for (int ni = 0; ni < 4; ni++) acc[mi][ni] = (f32x4){0.f, 0.f, 0.f, 0.f};

  short8 vah[2], val_[2], vbh[2], vbl[2];
  auto gld = [&](int kt) {
#pragma unroll
    for (int r = 0; r < 2; r++) {
      vah[r]  = *(const short8*)(Xh + ga[r] + kt);
      val_[r] = *(const short8*)(Xl + ga[r] + kt);
      vbh[r]  = *(const short8*)(WTh + gb[r] + kt);
      vbl[r]  = *(const short8*)(WTl + gb[r] + kt);
    }
  };

  gld(0);
  for (int it = 0; it < 24; it++) {
    __syncthreads();                       // prev frags consumed
#pragma unroll
    for (int r = 0; r < 2; r++) {
      *(short8*)&Ah[lofs[r]] = vah[r];
      *(short8*)&Al[lofs[r]] = val_[r];
      *(short8*)&Bh[lofs[r]] = vbh[r];
      *(short8*)&Bl[lofs[r]] = vbl[r];
    }
    __syncthreads();
    if (it < 23) gld((it + 1) * 32);       // fly next tile over the MFMAs

    short8 afh[4], afl[4], bfh[4], bfl[4];
#pragma unroll
    for (int mi = 0; mi < 4; mi++) {
      int r = (wm * 64 + mi * 16 + l16) * 40 + quad * 8;
      afh[mi] = *(const short8*)&Ah[r];
      afl[mi] = *(const short8*)&Al[r];
    }
#pragma unroll
    for (int ni = 0; ni < 4; ni++) {
      int r = (wn * 64 + ni * 16 + l16) * 40 + quad * 8;
      bfh[ni] = *(const short8*)&Bh[r];
      bfl[ni] = *(const short8*)&Bl[r];
    }
#pragma unroll
    for (int mi = 0; mi < 4; mi++)
#pragma unroll
      for (int ni = 0; ni < 4; ni++) {
        acc[mi][ni] = __builtin_amdgcn_mfma_f32_16x16x32_bf16(afh[mi], bfh[ni], acc[mi][ni], 0, 0, 0);
        acc[mi][ni] = __builtin_amdgcn_mfma_f32_16x16x32_bf16(afh[mi], bfl[ni], acc[mi][ni], 0, 0, 0);
        acc[mi][ni] = __builtin_amdgcn_mfma_f32_16x16x32_bf16(afl[mi], bfh[ni], acc[mi][ni], 0, 0, 0);
      }
  }

  int z = n0 / DB;                 // 0=Q 1=K 2=V, block-uniform
  int nl0 = n0 - z * DB;
  const float* bias = (z == 0) ? bq : ((z == 1) ? bk : bv);
#pragma unroll
  for (int mi = 0; mi < 4; mi++)
#pragma unroll
    for (int ni = 0; ni < 4; ni++)
#pragma unroll
      for (int r = 0; r < 4; r++) {
        int gm = m0 + wm * 64 + mi * 16 + quad * 4 + r;
        int ln = nl0 + wn * 64 + ni * 16 + l16;
        float val = acc[mi][ni][r] + bias[ln];
        unsigned short h = f2h_bits(val);
        if (z == 0) {
          Qf[(size_t)gm * DB + ln] = h;
        } else if (z == 1) {
          Kf[(size_t)gm * DB + ln] = h;
        } else {
          int bb = gm >> 11, s = gm & 2047;
          VT[((size_t)bb * DB + ln) * SEQ + s] = h;
        }
      }
}

// =============================================================================
// vmean: Vmean[b][n] = mean_s VT[b][n][s]  (VT fp16).
// =============================================================================
__global__ __launch_bounds__(256) void vmean_kernel(
    const unsigned short* __restrict__ VT, float* __restrict__ Vmean) {
  int bn = blockIdx.x;
  const unsigned short* p = VT + (size_t)bn * SEQ;
  int t = threadIdx.x, wave = t >> 6, lane = t & 63;
  short8 hv = *(const short8*)(p + t * 8);
  float s = 0.f;
#pragma unroll
  for (int j = 0; j < 8; j++) s += h2f_bits((unsigned short)hv[j]);
#pragma unroll
  for (int off = 32; off >= 1; off >>= 1) s += __shfl_down(s, off);
  __shared__ float red[4];
  if (lane == 0) red[wave] = s;
  __syncthreads();
  if (t == 0) Vmean[bn] = (red[0] + red[1] + red[2] + red[3]) * (1.0f / SEQ);
}

// =============================================================================
// scores (compacted q): SC[b][qc][t] = Qf[idx[qc]] . Kf[t], fp16 in/out.
// Single f16 MFMA (fp32 accumulate) — 3x fewer MFMAs, 2x fewer bytes.
// =============================================================================
__global__ __launch_bounds__(256) void scores_kernel(
    const unsigned short* __restrict__ Qf, const unsigned short* __restrict__ Kf,
    const int* __restrict__ idx, const int* __restrict__ cnt,
    unsigned short* __restrict__ SC) {
  __shared__ unsigned short As[128 * 40], Bs[128 * 40];   // 20 KB fp16 tiles
  int b = blockIdx.z;
  int cb = cnt[b];
  int q0 = blockIdx.y << 7;
  if (q0 >= cb) return;
  int t0 = blockIdx.x << 7;
  int tid = threadIdx.x;
  int wave = tid >> 6, lane = tid & 63;
  int wm = wave & 1, wn = wave >> 1;
  int quad = lane >> 4, l16 = lane & 15;

  size_t ga[2], gb[2]; int lofs[2];
#pragma unroll
  for (int r = 0; r < 2; r++) {
    int ix = (r << 11) + (tid << 3);
    int row = ix >> 5, col = ix & 31;
    int qr = q0 + row; if (qr >= cb) qr = cb - 1;   // clamp tail (writes guarded)
    int gq = idx[b * SEQ + qr];
    ga[r] = ((size_t)b * SEQ + gq) * DB + col;
    gb[r] = ((size_t)b * SEQ + t0 + row) * DB + col;
    lofs[r] = row * 40 + col;
  }

  f32x4 acc[4][4];
#pragma unroll
  for (int mi = 0; mi < 4; mi++)
#pragma unroll
    for (int ni = 0; ni < 4; ni++) acc[mi][ni] = (f32x4){0.f, 0.f, 0.f, 0.f};

  short8 va[2], vb[2];
  auto gld = [&](int kt) {
#pragma unroll
    for (int r = 0; r < 2; r++) {
      va[r] = *(const short8*)(Qf + ga[r] + kt);
      vb[r] = *(const short8*)(Kf + gb[r] + kt);
    }
  };

  gld(0);
  for (int it = 0; it < 24; it++) {
    __syncthreads();
#pragma unroll
    for (int r = 0; r < 2; r++) {
      *(short8*)&As[lofs[r]] = va[r];
      *(short8*)&Bs[lofs[r]] = vb[r];
    }
    __syncthreads();
    if (it < 23) gld((it + 1) * 32);

    half8 af[4], bfr[4];
#pragma unroll
    for (int mi = 0; mi < 4; mi++)
      af[mi] = *(const half8*)&As[(wm * 64 + mi * 16 + l16) * 40 + quad * 8];
#pragma unroll
    for (int ni = 0; ni < 4; ni++)
      bfr[ni] = *(const half8*)&Bs[(wn * 64 + ni * 16 + l16) * 40 + quad * 8];
#pragma unroll
    for (int mi = 0; mi < 4; mi++)
#pragma unroll
      for (int ni = 0; ni < 4; ni++)
        acc[mi][ni] = __builtin_amdgcn_mfma_f32_16x16x32_f16(af[mi], bfr[ni], acc[mi][ni], 0, 0, 0);
  }

#pragma unroll
  for (int mi = 0; mi < 4; mi++)
#pragma unroll
    for (int r = 0; r < 4; r++) {
      int qc = q0 + wm * 64 + mi * 16 + quad * 4 + r;
      if (qc < cb) {
#pragma unroll
        for (int ni = 0; ni < 4; ni++) {
          int gt = t0 + wn * 64 + ni * 16 + l16;
          SC[((size_t)b * SEQ + qc) * SEQ + gt] = f2h_bits(acc[mi][ni][r]);
        }
      }
    }
}

// =============================================================================
// softmax on compacted rows: fp16 scores -> fp16 (softmax * NORM * ASCALE).
// =============================================================================
__global__ __launch_bounds__(256) void softmax_kernel(
    unsigned short* __restrict__ SC, const int* __restrict__ cnt) {
  int b = blockIdx.x >> 11, qc = blockIdx.x & 2047;
  if (qc >= cnt[b]) return;
  unsigned short* p = SC + ((size_t)b * SEQ + qc) * SEQ;
  int tid = threadIdx.x;

  short8 hv = *(const short8*)(p + (tid << 3));
  float v[8];
#pragma unroll
  for (int j = 0; j < 8; j++) v[j] = h2f_bits((unsigned short)hv[j]);

  float m = v[0];
#pragma unroll
  for (int j = 1; j < 8; j++) m = fmaxf(m, v[j]);
#pragma unroll
  for (int off = 32; off >= 1; off >>= 1) m = fmaxf(m, __shfl_down(m, off));

  __shared__ float red[8];
  int w = tid >> 6;
  if ((tid & 63) == 0) red[w] = m;
  __syncthreads();
  m = fmaxf(fmaxf(red[0], red[1]), fmaxf(red[2], red[3]));

  float e[8], s = 0.f;
#pragma unroll
  for (int j = 0; j < 8; j++) { e[j] = __expf(v[j] - m); s += e[j]; }
#pragma unroll
  for (int off = 32; off >= 1; off >>= 1) s += __shfl_down(s, off);
  if ((tid & 63) == 0) red[4 + w] = s;
  __syncthreads();
  float L = red[4] + red[5] + red[6] + red[7];

  float scale = NORM_F * ASCALE / L;   // ASCALE undone in pv epilogue
  short8 ov;
#pragma unroll
  for (int j = 0; j < 8; j++) ov[j] = (short)f2h_bits(e[j] * scale);
  *(short8*)(p + (tid << 3)) = ov;
}

// =============================================================================
// fill: masked rows get NORM * mean(V).
// =============================================================================
__global__ __launch_bounds__(256) void fill_kernel(
    const int* __restrict__ mask, const float* __restrict__ Vmean,
    float* __restrict__ out) {
  int row = blockIdx.x;
  if (mask[row] != 0) return;
  const float* vm = Vmean + (row >> 11) * DB;
  float* o = out + (size_t)row * DB;
  for (int n = threadIdx.x; n < DB; n += 256) o[n] = vm[n] * NORM_F;
}

// =============================================================================
// pv (compacted): out[idx[qc]][v] = (1/ASCALE) * sum_t attn[qc][t] * V[t][v].
// fp16 attn + fp16 VT, f16 MFMA.
// =============================================================================
__global__ __launch_bounds__(256) void pv_kernel(
    const unsigned short* __restrict__ SC, const unsigned short* __restrict__ VT,
    const int* __restrict__ idx, const int* __restrict__ cnt,
    float* __restrict__ out) {
  __shared__ unsigned short As[128 * 40], Bs[128 * 40];
  int b = blockIdx.z;
  int cb = cnt[b];
  int q0 = blockIdx.y << 7;
  if (q0 >= cb) return;
  int v0 = blockIdx.x << 7;
  int tid = threadIdx.x;
  int wave = tid >> 6, lane = tid & 63;
  int wm = wave & 1, wn = wave >> 1;
  int quad = lane >> 4, l16 = lane & 15;

  size_t ga[2], gb[2]; int lofs[2];
#pragma unroll
  for (int r = 0; r < 2; r++) {
    int ix = (r << 11) + (tid << 3);
    int row = ix >> 5, col = ix & 31;
    ga[r] = ((size_t)b * SEQ + q0 + row) * SEQ + col;   // rows>=cb: garbage, guarded
    gb[r] = ((size_t)b * DB + v0 + row) * SEQ + col;
    lofs[r] = row * 40 + col;
  }

  f32x4 acc[4][4];
#pragma unroll
  for (int mi = 0; mi < 4; mi++)
#pragma unroll
    for (int ni = 0; ni < 4; ni++) acc[mi][ni] = (f32x4){0.f, 0.f, 0.f, 0.f};

  short8 va[2], vb[2];
  auto gld = [&](int kt) {
#pragma unroll
    for (int r = 0; r < 2; r++) {
      va[r] = *(const short8*)(SC + ga[r] + kt);
      vb[r] = *(const short8*)(VT + gb[r] + kt);
    }
  };

  gld(0);
  for (int it = 0; it < 64; it++) {
    __syncthreads();
#pragma unroll
    for (int r = 0; r < 2; r++) {
      *(short8*)&As[lofs[r]] = va[r];
      *(short8*)&Bs[lofs[r]] = vb[r];
    }
    __syncthreads();
    if (it < 63) gld((it + 1) * 32);

    half8 af[4], bfr[4];
#pragma unroll
    for (int mi = 0; mi < 4; mi++)
      af[mi] = *(const half8*)&As[(wm * 64 + mi * 16 + l16) * 40 + quad * 8];
#pragma unroll
    for (int ni = 0; ni < 4; ni++)
      bfr[ni] = *(const half8*)&Bs[(wn * 64 + ni * 16 + l16) * 40 + quad * 8];
#pragma unroll
    for (int mi = 0; mi < 4; mi++)
#pragma unroll
      for (int ni = 0; ni < 4; ni++)
        acc[mi][ni] = __builtin_amdgcn_mfma_f32_16x16x32_f16(af[mi], bfr[ni], acc[mi][ni], 0, 0, 0);
  }

#pragma unroll
  for (int mi = 0; mi < 4; mi++)
#pragma unroll
    for (int r = 0; r < 4; r++) {
      int qc = q0 + wm * 64 + mi * 16 + quad * 4 + r;
      if (qc < cb) {
        int q = idx[b * SEQ + qc];
#pragma unroll
        for (int ni = 0; ni < 4; ni++) {
          int gv = v0 + wn * 64 + ni * 16 + l16;
          out[((size_t)b * SEQ + q) * DB + gv] = acc[mi][ni][r] * INV_ASCALE;
        }
      }
    }
}

// =============================================================================
extern "C" void kernel_launch(void* const* d_in, const int* in_sizes, int n_in,
                              void* d_out, int out_size, void* d_ws, size_t ws_size,
                              hipStream_t stream) {
  const float* x    = (const float*)d_in[0];
  const int*   mask = (const int*)d_in[1];
  const float* Wq   = (const float*)d_in[2];
  const float* bq   = (const float*)d_in[3];
  const float* Wk   = (const float*)d_in[4];
  const float* bk   = (const float*)d_in[5];
  const float* Wv   = (const float*)d_in[6];
  const float* bv   = (const float*)d_in[7];
  float* out = (float*)d_out;
  char* ws = (char*)d_ws;

  // Workspace (~143 MB). SC region [0, 67.1MB) also hosts Xh/Xl/WTh/WTl,
  // which die when proj completes; scores then overwrites with SC.
  const size_t TOK2 = (size_t)NTOK * DB * 2;                 // 25,165,824 B
  unsigned short* SC  = (unsigned short*)ws;
  unsigned short* Xh  = (unsigned short*)ws;
  unsigned short* Xl  = (unsigned short*)(ws + TOK2);
  unsigned short* WTh = (unsigned short*)(ws + 2 * TOK2);
  unsigned short* WTl = (unsigned short*)(ws + 2 * TOK2 + (size_t)NFUSE * DB * 2);
  const size_t SCSZ = (size_t)BATCH * SEQ * SEQ * 2;         // 67,108,864 B
  unsigned short* Qf = (unsigned short*)(ws + SCSZ);
  unsigned short* Kf = Qf + (size_t)NTOK * DB;
  unsigned short* VT = Kf + (size_t)NTOK * DB;
  int*   idx   = (int*)(ws + SCSZ + 3 * TOK2);
  int*   cnt   = idx + NTOK;
  float* Vmean = (float*)(cnt + 16);

  wsplit_kernel<<<432, 256, 0, stream>>>(Wq, Wk, Wv, WTh, WTl);
  xsplit_kernel<<<NTOK * DB / 1024, 256, 0, stream>>>(x, Xh, Xl);
  compact_kernel<<<BATCH, 256, 0, stream>>>(mask, idx, cnt);
  proj_kernel<<<dim3(NFUSE / 128, NTOK / 128), 256, 0, stream>>>(
      Xh, Xl, WTh, WTl, bq, bk, bv, Qf, Kf, VT);
  vmean_kernel<<<BATCH * DB, 256, 0, stream>>>(VT, Vmean);
  scores_kernel<<<dim3(SEQ / 128, SEQ / 128, BATCH), 256, 0, stream>>>(
      Qf, Kf, idx, cnt, SC);
  softmax_kernel<<<NTOK, 256, 0, stream>>>(SC, cnt);
  fill_kernel<<<NTOK, 256, 0, stream>>>(mask, Vmean, out);
  pv_kernel<<<dim3(DB / 128, SEQ / 128, BATCH), 256, 0, stream>>>(
      SC, VT, idx, cnt, out);
}

// Round 6
// 360.672 us; speedup vs baseline: 2.6032x; 1.3516x over previous
//
#include <hip/hip_runtime.h>
#include <hip/hip_fp16.h>

#define DB    768
#define SEQ   2048
#define BATCH 8
#define NTOK  (BATCH*SEQ)      // 16384
#define NFUSE (3*DB)           // 2304 fused QKV output columns
#define NORM_F 0.036084391824351613f
#define ASCALE 512.0f          // attn stored *512 in fp16 to dodge denorm flush
#define INV_ASCALE (1.0f/512.0f)
#define LPAD 36                // LDS row stride (shorts): bank stride 18 -> <=2-way

typedef __attribute__((ext_vector_type(8))) short    short8;
typedef __attribute__((ext_vector_type(4))) short    short4v;
typedef __attribute__((ext_vector_type(8))) _Float16 half8;
typedef __attribute__((ext_vector_type(4))) float    f32x4;
typedef __attribute__((ext_vector_type(4))) float    float4v;

__device__ __forceinline__ float h2f_bits(unsigned short h) {
  __half v; __builtin_memcpy(&v, &h, 2); return __half2float(v);
}
__device__ __forceinline__ unsigned short f2h_bits(float f) {
  __half v = __float2half(f); unsigned short u; __builtin_memcpy(&u, &v, 2); return u;
}

// =============================================================================
// whalf: W[d][n] (3 weights) -> fused WT[nf][d] fp16, via LDS transpose.
// =============================================================================
__global__ __launch_bounds__(256) void whalf_kernel(
    const float* __restrict__ Wq, const float* __restrict__ Wk,
    const float* __restrict__ Wv, unsigned short* __restrict__ WT) {
  __shared__ float T[64][68];
  int bx = blockIdx.x;
  int w = bx / 144, rem = bx % 144;
  int d0 = (rem / 12) * 64, n0 = (rem % 12) * 64;
  const float* W = (w == 0) ? Wq : ((w == 1) ? Wk : Wv);
  int t = threadIdx.x;
  int dl = t >> 4, n4 = (t & 15) * 4;
#pragma unroll
  for (int j = 0; j < 4; j++) {
    float4v v = *(const float4v*)(W + (size_t)(d0 + dl + j * 16) * DB + n0 + n4);
    *(float4v*)&T[dl + j * 16][n4] = v;
  }
  __syncthreads();
  int nl = t >> 2, dc = (t & 3) * 16;
  short8 hb[2];
#pragma unroll
  for (int e = 0; e < 16; e++)
    hb[e >> 3][e & 7] = (short)f2h_bits(T[dc + e][nl]);
  size_t o = ((size_t)w * DB + n0 + nl) * DB + d0 + dc;
  *(short8*)(WT + o) = hb[0]; *(short8*)(WT + o + 8) = hb[1];
}

// =============================================================================
// xhalf: X fp32 -> Xf fp16.  grid 6144 (8 elems/thread)
// =============================================================================
__global__ __launch_bounds__(256) void xhalf_kernel(
    const float* __restrict__ X, unsigned short* __restrict__ Xf) {
  size_t i8 = ((size_t)blockIdx.x * 256 + threadIdx.x) * 8;
  float4v v0 = *(const float4v*)(X + i8);
  float4v v1 = *(const float4v*)(X + i8 + 4);
  short8 h;
#pragma unroll
  for (int j = 0; j < 4; j++) h[j] = (short)f2h_bits(v0[j]);
#pragma unroll
  for (int j = 0; j < 4; j++) h[4 + j] = (short)f2h_bits(v1[j]);
  *(short8*)(Xf + i8) = h;
}

// =============================================================================
// compact: per batch, list of unmasked q indices (ascending) + count.
// =============================================================================
__global__ __launch_bounds__(256) void compact_kernel(
    const int* __restrict__ mask, int* __restrict__ idx, int* __restrict__ cnt) {
  int b = blockIdx.x, t = threadIdx.x;
  const int* m = mask + b * SEQ;
  __shared__ int pref[256];
  int mv[8], c = 0, base = t * 8;
#pragma unroll
  for (int j = 0; j < 8; j++) { mv[j] = (m[base + j] != 0); c += mv[j]; }
  pref[t] = c;
  __syncthreads();
  for (int off = 1; off < 256; off <<= 1) {
    int add = (t >= off) ? pref[t - off] : 0;
    __syncthreads();
    pref[t] += add;
    __syncthreads();
  }
  int o = pref[t] - c;
  int* ib = idx + b * SEQ;
#pragma unroll
  for (int j = 0; j < 8; j++) if (mv[j]) ib[o++] = base + j;
  if (t == 255) cnt[b] = pref[255];
}

// =============================================================================
// proj: fused QKV GEMM, single fp16 MFMA (X,W fp16; fp32 accumulate).
// 128x128 tile BK=32, LDS pad-36 (conflict-free), VGPR prefetch of next tile.
// XCD swizzle: xcd g owns batch g's m-stripe; n outer, m inner (W+X L2-resident).
// =============================================================================
__global__ __launch_bounds__(256) void proj_kernel(
    const unsigned short* __restrict__ Xf, const unsigned short* __restrict__ WT,
    const float* __restrict__ bq, const float* __restrict__ bk,
    const float* __restrict__ bv,
    unsigned short* __restrict__ Qf, unsigned short* __restrict__ Kf,
    unsigned short* __restrict__ VT) {
  __shared__ unsigned short As[128 * LPAD], Bs[128 * LPAD];   // 18 KB
  int L = blockIdx.x;
  int g = L & 7, tt = L >> 3;                 // 2304 blocks: 288 per xcd
  int m0 = (g * 16 + (tt & 15)) << 7;         // batch-g rows
  int n0 = (tt >> 4) << 7;                    // n outer
  int tid = threadIdx.x;
  int wave = tid >> 6, lane = tid & 63;
  int wm = wave & 1, wn = wave >> 1;
  int quad = lane >> 4, l16 = lane & 15;

  size_t ga[2], gb[2]; int lofs[2];
#pragma unroll
  for (int r = 0; r < 2; r++) {
    int ix = (r << 11) + (tid << 3);
    int row = ix >> 5, col = ix & 31;
    ga[r] = (size_t)(m0 + row) * DB + col;
    gb[r] = (size_t)(n0 + row) * DB + col;
    lofs[r] = row * LPAD + col;
  }

  f32x4 acc[4][4];
#pragma unroll
  for (int mi = 0; mi < 4; mi++)
#pragma unroll
    for (int ni = 0; ni < 4; ni++) acc[mi][ni] = (f32x4){0.f, 0.f, 0.f, 0.f};

  short8 va[2], vb[2];
  auto gld = [&](int kt) {
#pragma unroll
    for (int r = 0; r < 2; r++) {
      va[r] = *(const short8*)(Xf + ga[r] + kt);
      vb[r] = *(const short8*)(WT + gb[r] + kt);
    }
  };

  gld(0);
  for (int it = 0; it < 24; it++) {
    __syncthreads();
#pragma unroll
    for (int r = 0; r < 2; r++) {
      *(short8*)&As[lofs[r]] = va[r];
      *(short8*)&Bs[lofs[r]] = vb[r];
    }
    __syncthreads();
    if (it < 23) gld((it + 1) * 32);        // fly next tile over the MFMAs

    half8 af[4], bfr[4];
#pragma unroll
    for (int mi = 0; mi < 4; mi++)
      af[mi] = *(const half8*)&As[(wm * 64 + mi * 16 + l16) * LPAD + quad * 8];
#pragma unroll
    for (int ni = 0; ni < 4; ni++)
      bfr[ni] = *(const half8*)&Bs[(wn * 64 + ni * 16 + l16) * LPAD + quad * 8];
#pragma unroll
    for (int mi = 0; mi < 4; mi++)
#pragma unroll
      for (int ni = 0; ni < 4; ni++)
        acc[mi][ni] = __builtin_amdgcn_mfma_f32_16x16x32_f16(af[mi], bfr[ni], acc[mi][ni], 0, 0, 0);
  }

  int z = n0 / DB;                 // 0=Q 1=K 2=V, block-uniform
  int nl0 = n0 - z * DB;
  const float* bias = (z == 0) ? bq : ((z == 1) ? bk : bv);
#pragma unroll
  for (int mi = 0; mi < 4; mi++)
#pragma unroll
    for (int ni = 0; ni < 4; ni++)
#pragma unroll
      for (int r = 0; r < 4; r++) {
        int gm = m0 + wm * 64 + mi * 16 + quad * 4 + r;
        int ln = nl0 + wn * 64 + ni * 16 + l16;
        unsigned short h = f2h_bits(acc[mi][ni][r] + bias[ln]);
        if (z == 0) {
          Qf[(size_t)gm * DB + ln] = h;
        } else if (z == 1) {
          Kf[(size_t)gm * DB + ln] = h;
        } else {
          int bb = gm >> 11, s = gm & 2047;
          VT[((size_t)bb * DB + ln) * SEQ + s] = h;
        }
      }
}

// =============================================================================
// vmean: Vmean[b][n] = mean_s VT[b][n][s]  (VT fp16).
// =============================================================================
__global__ __launch_bounds__(256) void vmean_kernel(
    const unsigned short* __restrict__ VT, float* __restrict__ Vmean) {
  int bn = blockIdx.x;
  const unsigned short* p = VT + (size_t)bn * SEQ;
  int t = threadIdx.x, wave = t >> 6, lane = t & 63;
  short8 hv = *(const short8*)(p + t * 8);
  float s = 0.f;
#pragma unroll
  for (int j = 0; j < 8; j++) s += h2f_bits((unsigned short)hv[j]);
#pragma unroll
  for (int off = 32; off >= 1; off >>= 1) s += __shfl_down(s, off);
  __shared__ float red[4];
  if (lane == 0) red[wave] = s;
  __syncthreads();
  if (t == 0) Vmean[bn] = (red[0] + red[1] + red[2] + red[3]) * (1.0f / SEQ);
}

// =============================================================================
// scores (compacted q): SC[b][qc][t] = Qf[idx[qc]] . Kf[t], fp16 in/out.
// XCD swizzle: xcd g owns batch g (K(b)=3MB L2-resident); q outer, t inner.
// =============================================================================
__global__ __launch_bounds__(256) void scores_kernel(
    const unsigned short* __restrict__ Qf, const unsigned short* __restrict__ Kf,
    const int* __restrict__ idx, const int* __restrict__ cnt,
    unsigned short* __restrict__ SC) {
  __shared__ unsigned short As[128 * LPAD], Bs[128 * LPAD];
  int L = blockIdx.x;
  int b = L & 7, tt = L >> 3;                 // 2048 blocks: 256 per xcd
  int q0 = (tt >> 4) << 7;                    // q outer
  int t0 = (tt & 15) << 7;                    // t inner
  int cb = cnt[b];
  if (q0 >= cb) return;
  int tid = threadIdx.x;
  int wave = tid >> 6, lane = tid & 63;
  int wm = wave & 1, wn = wave >> 1;
  int quad = lane >> 4, l16 = lane & 15;

  size_t ga[2], gb[2]; int lofs[2];
#pragma unroll
  for (int r = 0; r < 2; r++) {
    int ix = (r << 11) + (tid << 3);
    int row = ix >> 5, col = ix & 31;
    int qr = q0 + row; if (qr >= cb) qr = cb - 1;   // clamp tail (writes guarded)
    int gq = idx[b * SEQ + qr];
    ga[r] = ((size_t)b * SEQ + gq) * DB + col;
    gb[r] = ((size_t)b * SEQ + t0 + row) * DB + col;
    lofs[r] = row * LPAD + col;
  }

  f32x4 acc[4][4];
#pragma unroll
  for (int mi = 0; mi < 4; mi++)
#pragma unroll
    for (int ni = 0; ni < 4; ni++) acc[mi][ni] = (f32x4){0.f, 0.f, 0.f, 0.f};

  short8 va[2], vb[2];
  auto gld = [&](int kt) {
#pragma unroll
    for (int r = 0; r < 2; r++) {
      va[r] = *(const short8*)(Qf + ga[r] + kt);
      vb[r] = *(const short8*)(Kf + gb[r] + kt);
    }
  };

  gld(0);
  for (int it = 0; it < 24; it++) {
    __syncthreads();
#pragma unroll
    for (int r = 0; r < 2; r++) {
      *(short8*)&As[lofs[r]] = va[r];
      *(short8*)&Bs[lofs[r]] = vb[r];
    }
    __syncthreads();
    if (it < 23) gld((it + 1) * 32);

    half8 af[4], bfr[4];
#pragma unroll
    for (int mi = 0; mi < 4; mi++)
      af[mi] = *(const half8*)&As[(wm * 64 + mi * 16 + l16) * LPAD + quad * 8];
#pragma unroll
    for (int ni = 0; ni < 4; ni++)
      bfr[ni] = *(const half8*)&Bs[(wn * 64 + ni * 16 + l16) * LPAD + quad * 8];
#pragma unroll
    for (int mi = 0; mi < 4; mi++)
#pragma unroll
      for (int ni = 0; ni < 4; ni++)
        acc[mi][ni] = __builtin_amdgcn_mfma_f32_16x16x32_f16(af[mi], bfr[ni], acc[mi][ni], 0, 0, 0);
  }

#pragma unroll
  for (int mi = 0; mi < 4; mi++)
#pragma unroll
    for (int r = 0; r < 4; r++) {
      int qc = q0 + wm * 64 + mi * 16 + quad * 4 + r;
      if (qc < cb) {
#pragma unroll
        for (int ni = 0; ni < 4; ni++) {
          int gt = t0 + wn * 64 + ni * 16 + l16;
          SC[((size_t)b * SEQ + qc) * SEQ + gt] = f2h_bits(acc[mi][ni][r]);
        }
      }
    }
}

// =============================================================================
// softmax on compacted rows: fp16 scores -> fp16 (softmax * NORM * ASCALE).
// =============================================================================
__global__ __launch_bounds__(256) void softmax_kernel(
    unsigned short* __restrict__ SC, const int* __restrict__ cnt) {
  int b = blockIdx.x >> 11, qc = blockIdx.x & 2047;
  if (qc >= cnt[b]) return;
  unsigned short* p = SC + ((size_t)b * SEQ + qc) * SEQ;
  int tid = threadIdx.x;

  short8 hv = *(const short8*)(p + (tid << 3));
  float v[8];
#pragma unroll
  for (int j = 0; j < 8; j++) v[j] = h2f_bits((unsigned short)hv[j]);

  float m = v[0];
#pragma unroll
  for (int j = 1; j < 8; j++) m = fmaxf(m, v[j]);
#pragma unroll
  for (int off = 32; off >= 1; off >>= 1) m = fmaxf(m, __shfl_down(m, off));

  __shared__ float red[8];
  int w = tid >> 6;
  if ((tid & 63) == 0) red[w] = m;
  __syncthreads();
  m = fmaxf(fmaxf(red[0], red[1]), fmaxf(red[2], red[3]));

  float e[8], s = 0.f;
#pragma unroll
  for (int j = 0; j < 8; j++) { e[j] = __expf(v[j] - m); s += e[j]; }
#pragma unroll
  for (int off = 32; off >= 1; off >>= 1) s += __shfl_down(s, off);
  if ((tid & 63) == 0) red[4 + w] = s;
  __syncthreads();
  float L = red[4] + red[5] + red[6] + red[7];

  float scale = NORM_F * ASCALE / L;   // ASCALE undone in pv epilogue
  short8 ov;
#pragma unroll
  for (int j = 0; j < 8; j++) ov[j] = (short)f2h_bits(e[j] * scale);
  *(short8*)(p + (tid << 3)) = ov;
}

// =============================================================================
// fill: masked rows get NORM * mean(V).
// =============================================================================
__global__ __launch_bounds__(256) void fill_kernel(
    const int* __restrict__ mask, const float* __restrict__ Vmean,
    float* __restrict__ out) {
  int row = blockIdx.x;
  if (mask[row] != 0) return;
  const float* vm = Vmean + (row >> 11) * DB;
  float* o = out + (size_t)row * DB;
  for (int n = threadIdx.x; n < DB; n += 256) o[n] = vm[n] * NORM_F;
}

// =============================================================================
// pv (compacted): out[idx[qc]][v] = (1/ASCALE) * sum_t attn[qc][t] * V[t][v].
// XCD swizzle: xcd g owns batch g (VT(b)=3MB L2-resident); v inner per q-stripe.
// =============================================================================
__global__ __launch_bounds__(256) void pv_kernel(
    const unsigned short* __restrict__ SC, const unsigned short* __restrict__ VT,
    const int* __restrict__ idx, const int* __restrict__ cnt,
    float* __restrict__ out) {
  __shared__ unsigned short As[128 * LPAD], Bs[128 * LPAD];
  int L = blockIdx.x;
  int b = L & 7, tt = L >> 3;                 // 768 blocks: 96 per xcd
  int q0 = (tt / 6) << 7;                     // q outer
  int v0 = (tt % 6) << 7;                     // v inner (SC stripe reused 6x in L2)
  int cb = cnt[b];
  if (q0 >= cb) return;
  int tid = threadIdx.x;
  int wave = tid >> 6, lane = tid & 63;
  int wm = wave & 1, wn = wave >> 1;
  int quad = lane >> 4, l16 = lane & 15;

  size_t ga[2], gb[2]; int lofs[2];
#pragma unroll
  for (int r = 0; r < 2; r++) {
    int ix = (r << 11) + (tid << 3);
    int row = ix >> 5, col = ix & 31;
    ga[r] = ((size_t)b * SEQ + q0 + row) * SEQ + col;   // rows>=cb: garbage, guarded
    gb[r] = ((size_t)b * DB + v0 + row) * SEQ + col;
    lofs[r] = row * LPAD + col;
  }

  f32x4 acc[4][4];
#pragma unroll
  for (int mi = 0; mi < 4; mi++)
#pragma unroll
    for (int ni = 0; ni < 4; ni++) acc[mi][ni] = (f32x4){0.f, 0.f, 0.f, 0.f};

  short8 va[2], vb[2];
  auto gld = [&](int kt) {
#pragma unroll
    for (int r = 0; r < 2; r++) {
      va[r] = *(const short8*)(SC + ga[r] + kt);
      vb[r] = *(const short8*)(VT + gb[r] + kt);
    }
  };

  gld(0);
  for (int it = 0; it < 64; it++) {
    __syncthreads();
#pragma unroll
    for (int r = 0; r < 2; r++) {
      *(short8*)&As[lofs[r]] = va[r];
      *(short8*)&Bs[lofs[r]] = vb[r];
    }
    __syncthreads();
    if (it < 63) gld((it + 1) * 32);

    half8 af[4], bfr[4];
#pragma unroll
    for (int mi = 0; mi < 4; mi++)
      af[mi] = *(const half8*)&As[(wm * 64 + mi * 16 + l16) * LPAD + quad * 8];
#pragma unroll
    for (int ni = 0; ni < 4; ni++)
      bfr[ni] = *(const half8*)&Bs[(wn * 64 + ni * 16 + l16) * LPAD + quad * 8];
#pragma unroll
    for (int mi = 0; mi < 4; mi++)
#pragma unroll
      for (int ni = 0; ni < 4; ni++)
        acc[mi][ni] = __builtin_amdgcn_mfma_f32_16x16x32_f16(af[mi], bfr[ni], acc[mi][ni], 0, 0, 0);
  }

#pragma unroll
  for (int mi = 0; mi < 4; mi++)
#pragma unroll
    for (int r = 0; r < 4; r++) {
      int qc = q0 + wm * 64 + mi * 16 + quad * 4 + r;
      if (qc < cb) {
        int q = idx[b * SEQ + qc];
#pragma unroll
        for (int ni = 0; ni < 4; ni++) {
          int gv = v0 + wn * 64 + ni * 16 + l16;
          out[((size_t)b * SEQ + q) * DB + gv] = acc[mi][ni][r] * INV_ASCALE;
        }
      }
    }
}

// =============================================================================
extern "C" void kernel_launch(void* const* d_in, const int* in_sizes, int n_in,
                              void* d_out, int out_size, void* d_ws, size_t ws_size,
                              hipStream_t stream) {
  const float* x    = (const float*)d_in[0];
  const int*   mask = (const int*)d_in[1];
  const float* Wq   = (const float*)d_in[2];
  const float* bq   = (const float*)d_in[3];
  const float* Wk   = (const float*)d_in[4];
  const float* bk   = (const float*)d_in[5];
  const float* Wv   = (const float*)d_in[6];
  const float* bv   = (const float*)d_in[7];
  float* out = (float*)d_out;
  char* ws = (char*)d_ws;

  // Workspace (~143 MB). SC region [0, 67.1MB) also hosts Xf/WT, which die
  // when proj completes; scores then overwrites with SC.
  const size_t TOKH = (size_t)NTOK * DB * 2;                 // 25,165,824 B
  unsigned short* SC = (unsigned short*)ws;
  unsigned short* Xf = (unsigned short*)ws;
  unsigned short* WT = (unsigned short*)(ws + TOKH);
  const size_t SCSZ = (size_t)BATCH * SEQ * SEQ * 2;         // 67,108,864 B
  unsigned short* Qf = (unsigned short*)(ws + SCSZ);
  unsigned short* Kf = Qf + (size_t)NTOK * DB;
  unsigned short* VT = Kf + (size_t)NTOK * DB;
  int*   idx   = (int*)(ws + SCSZ + 3 * TOKH);
  int*   cnt   = idx + NTOK;
  float* Vmean = (float*)(cnt + 16);

  whalf_kernel<<<432, 256, 0, stream>>>(Wq, Wk, Wv, WT);
  xhalf_kernel<<<NTOK * DB / 2048, 256, 0, stream>>>(x, Xf);
  compact_kernel<<<BATCH, 256, 0, stream>>>(mask, idx, cnt);
  proj_kernel<<<NFUSE / 128 * (NTOK / 128), 256, 0, stream>>>(
      Xf, WT, bq, bk, bv, Qf, Kf, VT);
  vmean_kernel<<<BATCH * DB, 256, 0, stream>>>(VT, Vmean);
  scores_kernel<<<(SEQ / 128) * (SEQ / 128) * BATCH, 256, 0, stream>>>(
      Qf, Kf, idx, cnt, SC);
  softmax_kernel<<<NTOK, 256, 0, stream>>>(SC, cnt);
  fill_kernel<<<NTOK, 256, 0, stream>>>(mask, Vmean, out);
  pv_kernel<<<(DB / 128) * (SEQ / 128) * BATCH, 256, 0, stream>>>(
      SC, VT, idx, cnt, out);
}